// Round 9
// baseline (798.344 us; speedup 1.0000x reference)
//
#include <hip/hip_runtime.h>
#include <hip/hip_bf16.h>

// Problem constants (fixed by the reference)
constexpr int N_ = 2000;   // nodes
constexpr int E_ = 4096;   // edges
constexpr int H_ = 256;    // hidden
constexpr int KH_ = 128;   // he dim (mlp1 out)
constexpr int NV_ = H_ * KH_; // 32768, V row length (layout [o*128+k])
constexpr int MPAD_ = 2048;   // padded M for node-side MFMA GEMMs
constexpr int NG_ = 768;      // GRU gate width (3*H)

typedef short bf16x8 __attribute__((ext_vector_type(8)));
typedef float f32x4  __attribute__((ext_vector_type(4)));

__device__ __forceinline__ float bfu(unsigned short u) {
    return __uint_as_float(((unsigned)u) << 16);
}

// out = relu([emb[x], pos] @ lin0_W.T + b); emits Abf (bf16, zero-padded rows);
// also zeroes aggm for iteration 0.   grid MPAD_, block 256
__global__ void k_lin0(const int* __restrict__ x, const float* __restrict__ pos,
                       const float* __restrict__ emb, const float* __restrict__ W,
                       const float* __restrict__ b, float* __restrict__ out,
                       __hip_bfloat16* __restrict__ Abf, float* __restrict__ aggm) {
    int n = blockIdx.x, t = threadIdx.x;
    size_t idx = (size_t)n * H_ + t;
    if (idx < (size_t)N_ * H_) aggm[idx] = 0.f;
    if (n >= N_) { Abf[idx] = __float2bfloat16(0.f); return; }
    __shared__ float in_p[8];
    if (t < 5) in_p[t] = emb[x[n] * 5 + t];
    else if (t < 8) in_p[t] = pos[n * 3 + (t - 5)];
    __syncthreads();
    float acc = b[t];
#pragma unroll
    for (int i = 0; i < 8; i++) acc += in_p[i] * W[t * 8 + i];
    float v = fmaxf(acc, 0.f);
    out[idx] = v;
    Abf[idx] = __float2bfloat16(v);
}

// he = relu(edge_atr @ mlp1_W.T + b)   grid E, block 128
__global__ void k_he(const float* __restrict__ ea, const float* __restrict__ W,
                     const float* __restrict__ b, float* __restrict__ he) {
    int e = blockIdx.x, t = threadIdx.x;
    __shared__ float a[5];
    if (t < 5) a[t] = ea[e * 5 + t];
    __syncthreads();
    float acc = b[t];
#pragma unroll
    for (int i = 0; i < 5; i++) acc += a[i] * W[t * 5 + i];
    he[e * KH_ + t] = fmaxf(acc, 0.f);
}

__global__ void k_counts(const int* __restrict__ ei, float* __restrict__ counts) {
    int e = blockIdx.x * blockDim.x + threadIdx.x;
    if (e < E_) atomicAdd(&counts[ei[E_ + e]], 1.0f);
}

// --- edge bucketing by row-block (16 buckets of 128 rows), built once ---
__global__ void k_bucket_count(const int* __restrict__ ei, int* __restrict__ bcount) {
    int e = blockIdx.x * blockDim.x + threadIdx.x;
    if (e < E_) atomicAdd(&bcount[ei[e] >> 7], 1);
}
__global__ void k_bucket_scan(const int* __restrict__ bcount, int* __restrict__ bstart,
                              int* __restrict__ bfill) {
    if (threadIdx.x == 0) {
        int s = 0;
        for (int i = 0; i < 16; i++) { bstart[i] = s; bfill[i] = s; s += bcount[i]; }
        bstart[16] = s;
    }
}
__global__ void k_bucket_fill(const int* __restrict__ ei, int* __restrict__ bfill,
                              int* __restrict__ bucket) {
    int e = blockIdx.x * blockDim.x + threadIdx.x;
    if (e < E_) {
        int p = atomicAdd(&bfill[ei[e] >> 7], 1);
        bucket[p] = e;
    }
}

// Bt[n][k] = mlp2_W[k*32768 + n] as bf16 (transpose+convert), once per launch.
__global__ void k_trans_bt(const float* __restrict__ W, __hip_bfloat16* __restrict__ Bt) {
    __shared__ float tile[32][65];
    int t = threadIdx.x;
    int n0 = blockIdx.x * 64, k0 = blockIdx.y * 32;
#pragma unroll
    for (int i = 0; i < 8; i++) {
        int idx = t + i * 256;
        int kk = idx >> 6, nn = idx & 63;
        tile[kk][nn] = W[(size_t)(k0 + kk) * NV_ + n0 + nn];
    }
    __syncthreads();
#pragma unroll
    for (int i = 0; i < 8; i++) {
        int idx = t + i * 256;
        int nn = idx >> 5, kk = idx & 31;
        Bt[(size_t)(n0 + nn) * H_ + k0 + kk] = __float2bfloat16(tile[kk][nn]);
    }
}

// One-time weight preps (bf16 converts + lin2 pad + mlp2_b transpose).  grid 768, block 256
__global__ void k_prep_w(const float* __restrict__ Wih, const float* __restrict__ Whh,
                         const float* __restrict__ lin1W, const float* __restrict__ l6W1,
                         const float* __restrict__ lin2W, const float* __restrict__ b2,
                         __hip_bfloat16* __restrict__ WihB, __hip_bfloat16* __restrict__ WhhB,
                         __hip_bfloat16* __restrict__ lin1Wb, __hip_bfloat16* __restrict__ l6W1b,
                         __hip_bfloat16* __restrict__ lin2Wb, __hip_bfloat16* __restrict__ BtB) {
    int i = blockIdx.x * 256 + threadIdx.x;
    if (i < NG_ * H_) {
        WihB[i] = __float2bfloat16(Wih[i]);
        WhhB[i] = __float2bfloat16(Whh[i]);
    }
    if (i < H_ * 2 * H_) {
        lin1Wb[i] = __float2bfloat16(lin1W[i]);
    }
    if (i < 128 * 2 * H_) {
        l6W1b[i] = __float2bfloat16(l6W1[i]);
        int r = i >> 8, k = i & 255;
        lin2Wb[i] = __float2bfloat16(r < 242 ? lin2W[r * H_ + k] : 0.f);
        int o = i >> 8, h = i & 255;
        BtB[o * H_ + h] = __float2bfloat16(b2[h * H_ + o]);
    }
}

// Cbf[e] = bf16([h[row[e]], h[col[e]]])   grid E, block 256
__global__ void k_concat(const int* __restrict__ ei, const float* __restrict__ h,
                         __hip_bfloat16* __restrict__ Cbf) {
    int e = blockIdx.x, t = threadIdx.x;
    int r = ei[e], c = ei[E_ + e];
    Cbf[(size_t)e * 512 + t]       = __float2bfloat16(h[(size_t)r * H_ + t]);
    Cbf[(size_t)e * 512 + 256 + t] = __float2bfloat16(h[(size_t)c * H_ + t]);
}

// Generic MFMA GEMM: C(MxN) = A(MxKD bf16) @ Bt(NxKD bf16)^T [+bias][relu].
template <int KD, bool RELU, bool OUT_BF16>
__global__ __launch_bounds__(256) void k_gemm_nt(const __hip_bfloat16* __restrict__ A,
                                                 const __hip_bfloat16* __restrict__ Bt,
                                                 float* __restrict__ Cf,
                                                 __hip_bfloat16* __restrict__ Cb,
                                                 const float* __restrict__ bias,
                                                 int ldc, int ncols, int mvalid) {
    __shared__ short As[128 * 32];
    __shared__ short Bs[128 * 32];
    int t = threadIdx.x;
    int lane = t & 63, wave = t >> 6;
    int wm = wave >> 1, wn = wave & 1;
    int quad = lane >> 4, l16 = lane & 15;
    int row0 = blockIdx.y * 128, col0 = blockIdx.x * 128;

    f32x4 acc[4][4] = {};
    int r_ld = (lane >> 2);
    int koff = (lane & 3) * 8;

    for (int k0 = 0; k0 < KD; k0 += 32) {
#pragma unroll
        for (int c = 0; c < 4; c++) {
            int q = wave * 4 + c;
            int ch = q & 7;
            int r = ch * 16 + r_ld;
            const __hip_bfloat16* gp;
            short* lp;
            if (q < 8) { gp = A  + (size_t)(row0 + r) * KD + k0 + koff; lp = As + ch * 512; }
            else       { gp = Bt + (size_t)(col0 + r) * KD + k0 + koff; lp = Bs + ch * 512; }
            __builtin_amdgcn_global_load_lds(
                (const __attribute__((address_space(1))) unsigned int*)(uintptr_t)gp,
                (__attribute__((address_space(3))) unsigned int*)(uintptr_t)lp,
                16, 0, 0);
        }
        __syncthreads();
        bf16x8 a[4], b[4];
#pragma unroll
        for (int i = 0; i < 4; i++)
            a[i] = *(const bf16x8*)&As[(wm * 64 + i * 16 + l16) * 32 + quad * 8];
#pragma unroll
        for (int j = 0; j < 4; j++)
            b[j] = *(const bf16x8*)&Bs[(wn * 64 + j * 16 + l16) * 32 + quad * 8];
#pragma unroll
        for (int i = 0; i < 4; i++)
#pragma unroll
            for (int j = 0; j < 4; j++)
                acc[i][j] = __builtin_amdgcn_mfma_f32_16x16x32_bf16(a[i], b[j], acc[i][j], 0, 0, 0);
        __syncthreads();
    }

#pragma unroll
    for (int i = 0; i < 4; i++) {
        int gm0 = row0 + wm * 64 + i * 16 + quad * 4;
#pragma unroll
        for (int r = 0; r < 4; r++) {
            int gm = gm0 + r;
            if (gm < mvalid) {
#pragma unroll
                for (int j = 0; j < 4; j++) {
                    int col = col0 + wn * 64 + l16 + j * 16;
                    if (col < ncols) {
                        float v = acc[i][j][r];
                        if (bias) v += bias[col];
                        if (RELU) v = fmaxf(v, 0.f);
                        if (OUT_BF16) Cb[(size_t)gm * ldc + col] = __float2bfloat16(v);
                        else          Cf[(size_t)gm * ldc + col] = v;
                    }
                }
            }
        }
    }
}

// Fused V-GEMM + message pass. Grid (256, 16): x = output channel o (col-tile
// covers V cols [o*128, o*128+128) = all k for channel o; 256 % 8 == 0 keeps the
// col->XCD mapping fixed so each XCD's 2 MB B-stripe stays L2-resident).
// Block computes V_tile[128 rows][128 k] in registers, stages bf16 to LDS, then
// for each edge e with row in this stripe: msg = he[e,:].V_tile[row_e,:] +
// outb[row_e,o], atomicAdd into agg[col_e,o].  V never touches HBM.
__global__ __launch_bounds__(256) void k_gemm_V_msg(const __hip_bfloat16* __restrict__ A,
                                                    const __hip_bfloat16* __restrict__ Bt,
                                                    const int* __restrict__ ei,
                                                    const float* __restrict__ he,
                                                    const float* __restrict__ outb,
                                                    const int* __restrict__ bstart,
                                                    const int* __restrict__ bucket,
                                                    float* __restrict__ agg) {
    __shared__ __align__(16) char smem[128 * 132 * 2];   // 33792 B
    short* As = (short*)smem;                             // staging: 8 KB
    short* Bs = (short*)(smem + 8192);                    // staging: 8 KB
    short* Ps = (short*)smem;                             // epilogue: 128 x 132 bf16
    int t = threadIdx.x;
    int lane = t & 63, wave = t >> 6;
    int wm = wave >> 1, wn = wave & 1;
    int quad = lane >> 4, l16 = lane & 15;
    int row0 = blockIdx.y * 128;
    int o = blockIdx.x;
    int colbase = o * 128;

    f32x4 acc[4][4] = {};
    int r_ld = (lane >> 2);
    int koff = (lane & 3) * 8;

    for (int k0 = 0; k0 < H_; k0 += 32) {
#pragma unroll
        for (int c = 0; c < 4; c++) {
            int q = wave * 4 + c;
            int ch = q & 7;
            int r = ch * 16 + r_ld;
            const __hip_bfloat16* gp;
            short* lp;
            if (q < 8) { gp = A  + ((size_t)(row0 + r)    << 8) + k0 + koff; lp = As + ch * 512; }
            else       { gp = Bt + ((size_t)(colbase + r) << 8) + k0 + koff; lp = Bs + ch * 512; }
            __builtin_amdgcn_global_load_lds(
                (const __attribute__((address_space(1))) unsigned int*)(uintptr_t)gp,
                (__attribute__((address_space(3))) unsigned int*)(uintptr_t)lp,
                16, 0, 0);
        }
        __syncthreads();
        bf16x8 a[4], b[4];
#pragma unroll
        for (int i = 0; i < 4; i++)
            a[i] = *(const bf16x8*)&As[(wm * 64 + i * 16 + l16) * 32 + quad * 8];
#pragma unroll
        for (int j = 0; j < 4; j++)
            b[j] = *(const bf16x8*)&Bs[(wn * 64 + j * 16 + l16) * 32 + quad * 8];
#pragma unroll
        for (int i = 0; i < 4; i++)
#pragma unroll
            for (int j = 0; j < 4; j++)
                acc[i][j] = __builtin_amdgcn_mfma_f32_16x16x32_bf16(a[i], b[j], acc[i][j], 0, 0, 0);
        __syncthreads();
    }

    // stage V tile bf16 into LDS: Ps[row_local][k], stride 132 shorts (264 B:
    // 8B-aligned rows for b64 reads; 66 dwords -> bank rotation 2/row)
#pragma unroll
    for (int i = 0; i < 4; i++) {
        int rowb = wm * 64 + i * 16 + quad * 4;
#pragma unroll
        for (int r = 0; r < 4; r++) {
#pragma unroll
            for (int j = 0; j < 4; j++) {
                int kk = wn * 64 + j * 16 + l16;
                __hip_bfloat16 bv = __float2bfloat16(acc[i][j][r]);
                Ps[(rowb + r) * 132 + kk] = *(short*)&bv;
            }
        }
    }
    __syncthreads();

    // message pass: 16 groups of 16 lanes, one edge per group per pass
    int begin = bstart[blockIdx.y], end = bstart[blockIdx.y + 1];
    int g = wave * 4 + quad;
    for (int i = begin + g; i < end; i += 16) {
        int e = bucket[i];
        int r = ei[e], c = ei[E_ + e];
        int rl = r - row0;
        const float4* hp = (const float4*)(he + (size_t)e * KH_ + l16 * 8);
        float4 h0 = hp[0], h1 = hp[1];
        const short* pp = &Ps[rl * 132 + l16 * 8];
        ushort4 s0 = *(const ushort4*)pp;
        ushort4 s1 = *(const ushort4*)(pp + 4);
        float part = h0.x * bfu(s0.x) + h0.y * bfu(s0.y) + h0.z * bfu(s0.z) + h0.w * bfu(s0.w)
                   + h1.x * bfu(s1.x) + h1.y * bfu(s1.y) + h1.z * bfu(s1.z) + h1.w * bfu(s1.w);
        part += __shfl_xor(part, 1, 16);
        part += __shfl_xor(part, 2, 16);
        part += __shfl_xor(part, 4, 16);
        part += __shfl_xor(part, 8, 16);
        if (l16 == 0)
            atomicAdd(&agg[(size_t)c * H_ + o], part + outb[(size_t)r * H_ + o]);
    }
}

// GRU gates GEMM: z=0 -> gi = Mbf @ WihB^T + bih; z=1 -> gh = Abf @ WhhB^T + bhh.
__global__ __launch_bounds__(256) void k_gemm_gru_mfma(const __hip_bfloat16* __restrict__ A0,
                                                       const __hip_bfloat16* __restrict__ A1,
                                                       const __hip_bfloat16* __restrict__ W0,
                                                       const __hip_bfloat16* __restrict__ W1,
                                                       const float* __restrict__ b0,
                                                       const float* __restrict__ b1,
                                                       float* __restrict__ C0,
                                                       float* __restrict__ C1) {
    __shared__ short As[128 * 32];
    __shared__ short Bs[128 * 32];
    int t = threadIdx.x;
    int lane = t & 63, wave = t >> 6;
    int wm = wave >> 1, wn = wave & 1;
    int quad = lane >> 4, l16 = lane & 15;
    int row0 = blockIdx.y * 128, col0 = blockIdx.x * 128;
    const __hip_bfloat16* A  = blockIdx.z ? A1 : A0;
    const __hip_bfloat16* Bt = blockIdx.z ? W1 : W0;
    const float* bias        = blockIdx.z ? b1 : b0;
    float* C                 = blockIdx.z ? C1 : C0;

    f32x4 acc[4][4] = {};
    int r_ld = (lane >> 2);
    int koff = (lane & 3) * 8;

    for (int k0 = 0; k0 < H_; k0 += 32) {
#pragma unroll
        for (int c = 0; c < 4; c++) {
            int q = wave * 4 + c;
            int ch = q & 7;
            int r = ch * 16 + r_ld;
            const __hip_bfloat16* gp;
            short* lp;
            if (q < 8) { gp = A  + ((size_t)(row0 + r) << 8) + k0 + koff; lp = As + ch * 512; }
            else       { gp = Bt + ((size_t)(col0 + r) << 8) + k0 + koff; lp = Bs + ch * 512; }
            __builtin_amdgcn_global_load_lds(
                (const __attribute__((address_space(1))) unsigned int*)(uintptr_t)gp,
                (__attribute__((address_space(3))) unsigned int*)(uintptr_t)lp,
                16, 0, 0);
        }
        __syncthreads();
        bf16x8 a[4], b[4];
#pragma unroll
        for (int i = 0; i < 4; i++)
            a[i] = *(const bf16x8*)&As[(wm * 64 + i * 16 + l16) * 32 + quad * 8];
#pragma unroll
        for (int j = 0; j < 4; j++)
            b[j] = *(const bf16x8*)&Bs[(wn * 64 + j * 16 + l16) * 32 + quad * 8];
#pragma unroll
        for (int i = 0; i < 4; i++)
#pragma unroll
            for (int j = 0; j < 4; j++)
                acc[i][j] = __builtin_amdgcn_mfma_f32_16x16x32_bf16(a[i], b[j], acc[i][j], 0, 0, 0);
        __syncthreads();
    }

#pragma unroll
    for (int i = 0; i < 4; i++) {
        int gm0 = row0 + wm * 64 + i * 16 + quad * 4;
#pragma unroll
        for (int r = 0; r < 4; r++) {
            int gm = gm0 + r;
            if (gm < N_) {
                int col = col0 + wn * 64 + l16;
                size_t base = (size_t)gm * NG_ + col;
#pragma unroll
                for (int j = 0; j < 4; j++)
                    C[base + j * 16] = acc[i][j][r] + bias[col + j * 16];
            }
        }
    }
}

// Mbf = bf16(relu(agg / max(counts,1) + conv_b))
__global__ void k_m(const float* __restrict__ agg, const float* __restrict__ counts,
                    const float* __restrict__ conv_b, __hip_bfloat16* __restrict__ Mbf) {
    int i = blockIdx.x * blockDim.x + threadIdx.x;
    if (i >= N_ * H_) return;
    int n = i >> 8, o = i & 255;
    float c = fmaxf(counts[n], 1.0f);
    Mbf[i] = __float2bfloat16(fmaxf(agg[i] / c + conv_b[o], 0.f));
}

// GRU pointwise; refreshes Abf = bf16(h); re-zeroes aggm for the next iteration.
__global__ void k_gru_update(const float* __restrict__ gi, const float* __restrict__ gh,
                             float* __restrict__ h, __hip_bfloat16* __restrict__ Abf,
                             float* __restrict__ aggm) {
    int i = blockIdx.x * blockDim.x + threadIdx.x;
    if (i >= N_ * H_) return;
    aggm[i] = 0.f;
    int n = i >> 8, j = i & 255;
    const float* gip = gi + (size_t)n * NG_;
    const float* ghp = gh + (size_t)n * NG_;
    float r = 1.f / (1.f + expf(-(gip[j] + ghp[j])));
    float z = 1.f / (1.f + expf(-(gip[H_ + j] + ghp[H_ + j])));
    float nn = tanhf(gip[2 * H_ + j] + r * ghp[2 * H_ + j]);
    float hv = (1.f - z) * nn + z * h[i];
    h[i] = hv;
    Abf[i] = __float2bfloat16(hv);
}

// batchnorm stats over E rows, per column j   grid 128, block 256
__global__ void k_bnstats(const float* __restrict__ h1, float* __restrict__ mu,
                          float* __restrict__ rsig) {
    int j = blockIdx.x, t = threadIdx.x;
    float s = 0.f, ss = 0.f;
    for (int e = t; e < E_; e += 256) {
        float v = h1[(size_t)e * 128 + j];
        s += v;
        ss += v * v;
    }
    __shared__ float rs[256], rss[256];
    rs[t] = s; rss[t] = ss;
    __syncthreads();
    for (int off = 128; off > 0; off >>= 1) {
        if (t < off) { rs[t] += rs[t + off]; rss[t] += rss[t + off]; }
        __syncthreads();
    }
    if (t == 0) {
        float m_ = rs[0] / E_;
        float v_ = rss[0] / E_ - m_ * m_;
        mu[j] = m_;
        rsig[j] = rsqrtf(v_ + 1e-5f);
    }
}

// precs[e] = relu(bn(h1[e])) . l6_W2 + b
__global__ void k_precs(const float* __restrict__ h1, const float* __restrict__ mu,
                        const float* __restrict__ rsig, const float* __restrict__ g,
                        const float* __restrict__ bb, const float* __restrict__ W2,
                        const float* __restrict__ b2, float* __restrict__ out) {
    int e = blockIdx.x * blockDim.x + threadIdx.x;
    if (e >= E_) return;
    float acc = b2[0];
#pragma unroll 4
    for (int j = 0; j < 128; j++) {
        float v = (h1[(size_t)e * 128 + j] - mu[j]) * rsig[j] * g[j] + bb[j];
        acc += fmaxf(v, 0.f) * W2[j];
    }
    out[(size_t)E_ * 242 + e] = acc;
}

extern "C" void kernel_launch(void* const* d_in, const int* in_sizes, int n_in,
                              void* d_out, int out_size, void* d_ws, size_t ws_size,
                              hipStream_t stream) {
    const int*   x        = (const int*)  d_in[0];
    const float* pos      = (const float*)d_in[1];
    const int*   ei       = (const int*)  d_in[2];
    const float* edge_atr = (const float*)d_in[3];
    const float* emb      = (const float*)d_in[4];
    const float* lin0_W   = (const float*)d_in[5];
    const float* lin0_b   = (const float*)d_in[6];
    const float* mlp1_W   = (const float*)d_in[7];
    const float* mlp1_b   = (const float*)d_in[8];
    const float* mlp2_W   = (const float*)d_in[9];
    const float* mlp2_b   = (const float*)d_in[10];
    const float* conv_b   = (const float*)d_in[11];
    const float* gru_Wih  = (const float*)d_in[12];
    const float* gru_Whh  = (const float*)d_in[13];
    const float* gru_bih  = (const float*)d_in[14];
    const float* gru_bhh  = (const float*)d_in[15];
    const float* lin1_W   = (const float*)d_in[16];
    const float* lin1_b   = (const float*)d_in[17];
    const float* lin2_W   = (const float*)d_in[18];
    const float* lin2_b   = (const float*)d_in[19];
    const float* l6_W1    = (const float*)d_in[20];
    const float* l6_b1    = (const float*)d_in[21];
    const float* bn_g     = (const float*)d_in[22];
    const float* bn_b     = (const float*)d_in[23];
    const float* l6_W2    = (const float*)d_in[24];
    const float* l6_b2    = (const float*)d_in[25];
    float* out = (float*)d_out;

    // workspace layout
    char* w = (char*)d_ws;
    size_t off = 0;
    auto alloc = [&](size_t bytes) -> void* {
        void* p = w + off;
        off = (off + bytes + 255) & ~(size_t)255;
        return p;
    };
    float* hbuf   = (float*)alloc((size_t)N_ * H_ * 4);
    float* aggm   = (float*)alloc((size_t)N_ * H_ * 4);
    float* outb   = (float*)alloc((size_t)N_ * H_ * 4);
    float* he     = (float*)alloc((size_t)E_ * KH_ * 4);
    float* gi     = (float*)alloc((size_t)N_ * NG_ * 4);
    float* gh     = (float*)alloc((size_t)N_ * NG_ * 4);
    float* h1     = (float*)alloc((size_t)E_ * 128 * 4);
    float* counts = (float*)alloc((size_t)N_ * 4);
    float* mu     = (float*)alloc(128 * 4);
    float* rsig   = (float*)alloc(128 * 4);
    int* bcount   = (int*)alloc(16 * 4);
    int* bstart   = (int*)alloc(17 * 4);
    int* bfill    = (int*)alloc(16 * 4);
    int* bucket   = (int*)alloc((size_t)E_ * 4);
    __hip_bfloat16* Abf    = (__hip_bfloat16*)alloc((size_t)MPAD_ * H_ * 2);
    __hip_bfloat16* Mbf    = (__hip_bfloat16*)alloc((size_t)MPAD_ * H_ * 2);
    __hip_bfloat16* Bt     = (__hip_bfloat16*)alloc((size_t)NV_ * H_ * 2);     // 16.8 MB
    __hip_bfloat16* WihB   = (__hip_bfloat16*)alloc((size_t)NG_ * H_ * 2);
    __hip_bfloat16* WhhB   = (__hip_bfloat16*)alloc((size_t)NG_ * H_ * 2);
    __hip_bfloat16* lin1Wb = (__hip_bfloat16*)alloc((size_t)H_ * 2 * H_ * 2);
    __hip_bfloat16* l6W1b  = (__hip_bfloat16*)alloc((size_t)128 * 2 * H_ * 2);
    __hip_bfloat16* lin2Wb = (__hip_bfloat16*)alloc((size_t)H_ * H_ * 2);
    __hip_bfloat16* BtB    = (__hip_bfloat16*)alloc((size_t)H_ * H_ * 2);
    __hip_bfloat16* Cbf    = (__hip_bfloat16*)alloc((size_t)E_ * 2 * H_ * 2);
    __hip_bfloat16* o1bf   = (__hip_bfloat16*)alloc((size_t)E_ * H_ * 2);

    k_lin0<<<MPAD_, 256, 0, stream>>>(x, pos, emb, lin0_W, lin0_b, hbuf, Abf, aggm);
    k_he<<<E_, 128, 0, stream>>>(edge_atr, mlp1_W, mlp1_b, he);
    hipMemsetAsync(counts, 0, (size_t)N_ * 4, stream);
    hipMemsetAsync(bcount, 0, 16 * 4, stream);
    k_counts<<<(E_ + 255) / 256, 256, 0, stream>>>(ei, counts);
    k_bucket_count<<<(E_ + 255) / 256, 256, 0, stream>>>(ei, bcount);
    k_bucket_scan<<<1, 64, 0, stream>>>(bcount, bstart, bfill);
    k_bucket_fill<<<(E_ + 255) / 256, 256, 0, stream>>>(ei, bfill, bucket);
    k_trans_bt<<<dim3(NV_ / 64, H_ / 32), 256, 0, stream>>>(mlp2_W, Bt);
    k_prep_w<<<768, 256, 0, stream>>>(gru_Wih, gru_Whh, lin1_W, l6_W1, lin2_W, mlp2_b,
                                      WihB, WhhB, lin1Wb, l6W1b, lin2Wb, BtB);

    for (int it = 0; it < 3; it++) {
        // outb = Abf @ BtB^T (fp32, no bias) — must precede the fused V+msg kernel
        k_gemm_nt<256, false, false><<<dim3(2, MPAD_ / 128), 256, 0, stream>>>(
            Abf, BtB, outb, nullptr, nullptr, H_, H_, N_);
        // fused V-GEMM + message pass (V stays on-chip)
        k_gemm_V_msg<<<dim3(256, MPAD_ / 128), 256, 0, stream>>>(
            Abf, Bt, ei, he, outb, bstart, bucket, aggm);
        k_m<<<(N_ * H_ + 255) / 256, 256, 0, stream>>>(aggm, counts, conv_b, Mbf);
        dim3 gg(NG_ / 128, MPAD_ / 128, 2);
        k_gemm_gru_mfma<<<gg, 256, 0, stream>>>(Mbf, Abf, WihB, WhhB,
                                                gru_bih, gru_bhh, gi, gh);
        k_gru_update<<<(N_ * H_ + 255) / 256, 256, 0, stream>>>(gi, gh, hbuf, Abf, aggm);
    }

    k_concat<<<E_, 256, 0, stream>>>(ei, hbuf, Cbf);
    k_gemm_nt<512, true, true><<<dim3(2, E_ / 128), 256, 0, stream>>>(
        Cbf, lin1Wb, nullptr, o1bf, lin1_b, H_, H_, E_);
    k_gemm_nt<256, false, false><<<dim3(2, E_ / 128), 256, 0, stream>>>(
        o1bf, lin2Wb, out, nullptr, lin2_b, 242, 242, E_);
    k_gemm_nt<512, false, false><<<dim3(1, E_ / 128), 256, 0, stream>>>(
        Cbf, l6W1b, h1, nullptr, l6_b1, 128, 128, E_);
    k_bnstats<<<128, 256, 0, stream>>>(h1, mu, rsig);
    k_precs<<<(E_ + 255) / 256, 256, 0, stream>>>(h1, mu, rsig, bn_g, bn_b, l6_W2, l6_b2, out);
}

// Round 10
// 558.527 us; speedup vs baseline: 1.4294x; 1.4294x over previous
//
#include <hip/hip_runtime.h>
#include <hip/hip_bf16.h>

// Problem constants (fixed by the reference)
constexpr int N_ = 2000;   // nodes
constexpr int E_ = 4096;   // edges
constexpr int H_ = 256;    // hidden
constexpr int KH_ = 128;   // he dim (mlp1 out)
constexpr int NV_ = H_ * KH_; // 32768, V row length (layout [o*128+k]) — fp8 bytes
constexpr int MPAD_ = 2048;   // padded M for node-side MFMA GEMMs
constexpr int NG_ = 768;      // GRU gate width (3*H)
constexpr float VSCALE = 64.f;     // fp8 scale for V (avoids e4m3 subnormals)
constexpr float VSCALE_INV = 1.f / 64.f;

typedef short bf16x8 __attribute__((ext_vector_type(8)));
typedef float f32x4  __attribute__((ext_vector_type(4)));
typedef float f32x2  __attribute__((ext_vector_type(2)));

__device__ __forceinline__ float bf_lo(unsigned u) { return __uint_as_float(u << 16); }
__device__ __forceinline__ float bf_hi(unsigned u) { return __uint_as_float(u & 0xffff0000u); }

// out = relu([emb[x], pos] @ lin0_W.T + b); emits Abf (bf16, zero-padded rows);
// also zeroes aggm for iteration 0.   grid MPAD_, block 256
__global__ void k_lin0(const int* __restrict__ x, const float* __restrict__ pos,
                       const float* __restrict__ emb, const float* __restrict__ W,
                       const float* __restrict__ b, float* __restrict__ out,
                       __hip_bfloat16* __restrict__ Abf, float* __restrict__ aggm) {
    int n = blockIdx.x, t = threadIdx.x;
    size_t idx = (size_t)n * H_ + t;
    if (idx < (size_t)N_ * H_) aggm[idx] = 0.f;
    if (n >= N_) { Abf[idx] = __float2bfloat16(0.f); return; }
    __shared__ float in_p[8];
    if (t < 5) in_p[t] = emb[x[n] * 5 + t];
    else if (t < 8) in_p[t] = pos[n * 3 + (t - 5)];
    __syncthreads();
    float acc = b[t];
#pragma unroll
    for (int i = 0; i < 8; i++) acc += in_p[i] * W[t * 8 + i];
    float v = fmaxf(acc, 0.f);
    out[idx] = v;
    Abf[idx] = __float2bfloat16(v);
}

// he = relu(edge_atr @ mlp1_W.T + b)   grid E, block 128
__global__ void k_he(const float* __restrict__ ea, const float* __restrict__ W,
                     const float* __restrict__ b, float* __restrict__ he) {
    int e = blockIdx.x, t = threadIdx.x;
    __shared__ float a[5];
    if (t < 5) a[t] = ea[e * 5 + t];
    __syncthreads();
    float acc = b[t];
#pragma unroll
    for (int i = 0; i < 5; i++) acc += a[i] * W[t * 5 + i];
    he[e * KH_ + t] = fmaxf(acc, 0.f);
}

__global__ void k_counts(const int* __restrict__ ei, float* __restrict__ counts) {
    int e = blockIdx.x * blockDim.x + threadIdx.x;
    if (e < E_) atomicAdd(&counts[ei[E_ + e]], 1.0f);
}

// Bt[n][k] = mlp2_W[k*32768 + n] as bf16 (transpose+convert), once per launch.
__global__ void k_trans_bt(const float* __restrict__ W, __hip_bfloat16* __restrict__ Bt) {
    __shared__ float tile[32][65];
    int t = threadIdx.x;
    int n0 = blockIdx.x * 64, k0 = blockIdx.y * 32;
#pragma unroll
    for (int i = 0; i < 8; i++) {
        int idx = t + i * 256;
        int kk = idx >> 6, nn = idx & 63;
        tile[kk][nn] = W[(size_t)(k0 + kk) * NV_ + n0 + nn];
    }
    __syncthreads();
#pragma unroll
    for (int i = 0; i < 8; i++) {
        int idx = t + i * 256;
        int nn = idx >> 5, kk = idx & 31;
        Bt[(size_t)(n0 + nn) * H_ + k0 + kk] = __float2bfloat16(tile[kk][nn]);
    }
}

// One-time weight preps (bf16 converts + lin2 pad + mlp2_b transpose).  grid 768, block 256
__global__ void k_prep_w(const float* __restrict__ Wih, const float* __restrict__ Whh,
                         const float* __restrict__ lin1W, const float* __restrict__ l6W1,
                         const float* __restrict__ lin2W, const float* __restrict__ b2,
                         __hip_bfloat16* __restrict__ WihB, __hip_bfloat16* __restrict__ WhhB,
                         __hip_bfloat16* __restrict__ lin1Wb, __hip_bfloat16* __restrict__ l6W1b,
                         __hip_bfloat16* __restrict__ lin2Wb, __hip_bfloat16* __restrict__ BtB) {
    int i = blockIdx.x * 256 + threadIdx.x;
    if (i < NG_ * H_) {
        WihB[i] = __float2bfloat16(Wih[i]);
        WhhB[i] = __float2bfloat16(Whh[i]);
    }
    if (i < H_ * 2 * H_) {
        lin1Wb[i] = __float2bfloat16(lin1W[i]);
    }
    if (i < 128 * 2 * H_) {
        l6W1b[i] = __float2bfloat16(l6W1[i]);
        int r = i >> 8, k = i & 255;
        lin2Wb[i] = __float2bfloat16(r < 242 ? lin2W[r * H_ + k] : 0.f);
        int o = i >> 8, h = i & 255;
        BtB[o * H_ + h] = __float2bfloat16(b2[h * H_ + o]);
    }
}

// Cbf[e] = bf16([h[row[e]], h[col[e]]])   grid E, block 256
__global__ void k_concat(const int* __restrict__ ei, const float* __restrict__ h,
                         __hip_bfloat16* __restrict__ Cbf) {
    int e = blockIdx.x, t = threadIdx.x;
    int r = ei[e], c = ei[E_ + e];
    Cbf[(size_t)e * 512 + t]       = __float2bfloat16(h[(size_t)r * H_ + t]);
    Cbf[(size_t)e * 512 + 256 + t] = __float2bfloat16(h[(size_t)c * H_ + t]);
}

// Generic MFMA GEMM: C(MxN) = A(MxKD bf16) @ Bt(NxKD bf16)^T [+bias][relu].
template <int KD, bool RELU, bool OUT_BF16>
__global__ __launch_bounds__(256) void k_gemm_nt(const __hip_bfloat16* __restrict__ A,
                                                 const __hip_bfloat16* __restrict__ Bt,
                                                 float* __restrict__ Cf,
                                                 __hip_bfloat16* __restrict__ Cb,
                                                 const float* __restrict__ bias,
                                                 int ldc, int ncols, int mvalid) {
    __shared__ short As[128 * 32];
    __shared__ short Bs[128 * 32];
    int t = threadIdx.x;
    int lane = t & 63, wave = t >> 6;
    int wm = wave >> 1, wn = wave & 1;
    int quad = lane >> 4, l16 = lane & 15;
    int row0 = blockIdx.y * 128, col0 = blockIdx.x * 128;

    f32x4 acc[4][4] = {};
    int r_ld = (lane >> 2);
    int koff = (lane & 3) * 8;

    for (int k0 = 0; k0 < KD; k0 += 32) {
#pragma unroll
        for (int c = 0; c < 4; c++) {
            int q = wave * 4 + c;
            int ch = q & 7;
            int r = ch * 16 + r_ld;
            const __hip_bfloat16* gp;
            short* lp;
            if (q < 8) { gp = A  + (size_t)(row0 + r) * KD + k0 + koff; lp = As + ch * 512; }
            else       { gp = Bt + (size_t)(col0 + r) * KD + k0 + koff; lp = Bs + ch * 512; }
            __builtin_amdgcn_global_load_lds(
                (const __attribute__((address_space(1))) unsigned int*)(uintptr_t)gp,
                (__attribute__((address_space(3))) unsigned int*)(uintptr_t)lp,
                16, 0, 0);
        }
        __syncthreads();
        bf16x8 a[4], b[4];
#pragma unroll
        for (int i = 0; i < 4; i++)
            a[i] = *(const bf16x8*)&As[(wm * 64 + i * 16 + l16) * 32 + quad * 8];
#pragma unroll
        for (int j = 0; j < 4; j++)
            b[j] = *(const bf16x8*)&Bs[(wn * 64 + j * 16 + l16) * 32 + quad * 8];
#pragma unroll
        for (int i = 0; i < 4; i++)
#pragma unroll
            for (int j = 0; j < 4; j++)
                acc[i][j] = __builtin_amdgcn_mfma_f32_16x16x32_bf16(a[i], b[j], acc[i][j], 0, 0, 0);
        __syncthreads();
    }

#pragma unroll
    for (int i = 0; i < 4; i++) {
        int gm0 = row0 + wm * 64 + i * 16 + quad * 4;
#pragma unroll
        for (int r = 0; r < 4; r++) {
            int gm = gm0 + r;
            if (gm < mvalid) {
#pragma unroll
                for (int j = 0; j < 4; j++) {
                    int col = col0 + wn * 64 + l16 + j * 16;
                    if (col < ncols) {
                        float v = acc[i][j][r];
                        if (bias) v += bias[col];
                        if (RELU) v = fmaxf(v, 0.f);
                        if (OUT_BF16) Cb[(size_t)gm * ldc + col] = __float2bfloat16(v);
                        else          Cf[(size_t)gm * ldc + col] = v;
                    }
                }
            }
        }
    }
}

// V = Abf(2048x256) @ Bt^T(32768x256) -> fp8 e4m3 (x64 scale).
// Grid (256, 16): blockIdx.x = COL-block fastest, 256 % 8 == 0 so the col->XCD
// round-robin mapping is FIXED per column stripe — each XCD's 2 MB B-stripe stays
// L2-resident (r5-verified: FETCH 44 MB vs 136 MB when gridDim.x=258).
// LDS: staging (16 KB) unioned with 64-row epilogue repack (17.4 KB). Plain stores.
__global__ __launch_bounds__(256) void k_gemm_V_mfma(const __hip_bfloat16* __restrict__ A,
                                                     const __hip_bfloat16* __restrict__ Bt,
                                                     unsigned char* __restrict__ V8) {
    __shared__ __align__(16) char smem[64 * 136 * 2];   // 17408 B
    short* As = (short*)smem;                            // 128*32 shorts = 8 KB
    short* Bs = (short*)(smem + 8192);                   // 8 KB
    short* Ps = (short*)smem;                            // 64*136 shorts (epilogue only)
    int t = threadIdx.x;
    int lane = t & 63, wave = t >> 6;
    int wm = wave >> 1, wn = wave & 1;
    int quad = lane >> 4, l16 = lane & 15;
    int row0 = blockIdx.y * 128;
    int colbase = blockIdx.x * 128;

    f32x4 acc[4][4] = {};
    int r_ld = (lane >> 2);
    int koff = (lane & 3) * 8;

    for (int k0 = 0; k0 < H_; k0 += 32) {
#pragma unroll
        for (int c = 0; c < 4; c++) {
            int q = wave * 4 + c;
            int ch = q & 7;
            int r = ch * 16 + r_ld;
            const __hip_bfloat16* gp;
            short* lp;
            if (q < 8) { gp = A  + ((size_t)(row0 + r)    << 8) + k0 + koff; lp = As + ch * 512; }
            else       { gp = Bt + ((size_t)(colbase + r) << 8) + k0 + koff; lp = Bs + ch * 512; }
            __builtin_amdgcn_global_load_lds(
                (const __attribute__((address_space(1))) unsigned int*)(uintptr_t)gp,
                (__attribute__((address_space(3))) unsigned int*)(uintptr_t)lp,
                16, 0, 0);
        }
        __syncthreads();
        bf16x8 a[4], b[4];
#pragma unroll
        for (int i = 0; i < 4; i++)
            a[i] = *(const bf16x8*)&As[(wm * 64 + i * 16 + l16) * 32 + quad * 8];
#pragma unroll
        for (int j = 0; j < 4; j++)
            b[j] = *(const bf16x8*)&Bs[(wn * 64 + j * 16 + l16) * 32 + quad * 8];
#pragma unroll
        for (int i = 0; i < 4; i++)
#pragma unroll
            for (int j = 0; j < 4; j++)
                acc[i][j] = __builtin_amdgcn_mfma_f32_16x16x32_bf16(a[i], b[j], acc[i][j], 0, 0, 0);
        __syncthreads();
    }

    // two 64-row half-passes through the unioned LDS repack buffer.
#pragma unroll
    for (int half = 0; half < 2; half++) {
        if (wm == half) {
#pragma unroll
            for (int i = 0; i < 4; i++) {
                int rowb = i * 16 + quad * 4;     // local row within the half
#pragma unroll
                for (int r = 0; r < 4; r++) {
#pragma unroll
                    for (int j = 0; j < 4; j++) {
                        int col = wn * 64 + j * 16 + l16;
                        __hip_bfloat16 bv = __float2bfloat16(acc[i][j][r] * VSCALE);
                        Ps[(rowb + r) * 136 + col] = *(short*)&bv;
                    }
                }
            }
        }
        __syncthreads();
        // coalesced fp8 copy-out: 64x128 elems, 8/thread/pass, 4 passes
#pragma unroll
        for (int p = 0; p < 4; p++) {
            int e = (p * 256 + t) * 8;
            int row = e >> 7, col = e & 127;
            int gm = row0 + half * 64 + row;
            if (gm < N_) {
                uint4 u = *(const uint4*)&Ps[row * 136 + col];
                float f0 = bf_lo(u.x), f1 = bf_hi(u.x), f2 = bf_lo(u.y), f3 = bf_hi(u.y);
                float f4 = bf_lo(u.z), f5 = bf_hi(u.z), f6 = bf_lo(u.w), f7 = bf_hi(u.w);
                unsigned px = __builtin_amdgcn_cvt_pk_fp8_f32(f0, f1, 0, false);
                px = __builtin_amdgcn_cvt_pk_fp8_f32(f2, f3, px, true);
                unsigned py = __builtin_amdgcn_cvt_pk_fp8_f32(f4, f5, 0, false);
                py = __builtin_amdgcn_cvt_pk_fp8_f32(f6, f7, py, true);
                uint2 o2; o2.x = px; o2.y = py;
                *(uint2*)(V8 + (size_t)gm * NV_ + colbase + col) = o2;
            }
        }
        __syncthreads();
    }
}

// GRU gates GEMM: z=0 -> gi = Mbf @ WihB^T + bih; z=1 -> gh = Abf @ WhhB^T + bhh.
__global__ __launch_bounds__(256) void k_gemm_gru_mfma(const __hip_bfloat16* __restrict__ A0,
                                                       const __hip_bfloat16* __restrict__ A1,
                                                       const __hip_bfloat16* __restrict__ W0,
                                                       const __hip_bfloat16* __restrict__ W1,
                                                       const float* __restrict__ b0,
                                                       const float* __restrict__ b1,
                                                       float* __restrict__ C0,
                                                       float* __restrict__ C1) {
    __shared__ short As[128 * 32];
    __shared__ short Bs[128 * 32];
    int t = threadIdx.x;
    int lane = t & 63, wave = t >> 6;
    int wm = wave >> 1, wn = wave & 1;
    int quad = lane >> 4, l16 = lane & 15;
    int row0 = blockIdx.y * 128, col0 = blockIdx.x * 128;
    const __hip_bfloat16* A  = blockIdx.z ? A1 : A0;
    const __hip_bfloat16* Bt = blockIdx.z ? W1 : W0;
    const float* bias        = blockIdx.z ? b1 : b0;
    float* C                 = blockIdx.z ? C1 : C0;

    f32x4 acc[4][4] = {};
    int r_ld = (lane >> 2);
    int koff = (lane & 3) * 8;

    for (int k0 = 0; k0 < H_; k0 += 32) {
#pragma unroll
        for (int c = 0; c < 4; c++) {
            int q = wave * 4 + c;
            int ch = q & 7;
            int r = ch * 16 + r_ld;
            const __hip_bfloat16* gp;
            short* lp;
            if (q < 8) { gp = A  + ((size_t)(row0 + r) << 8) + k0 + koff; lp = As + ch * 512; }
            else       { gp = Bt + ((size_t)(col0 + r) << 8) + k0 + koff; lp = Bs + ch * 512; }
            __builtin_amdgcn_global_load_lds(
                (const __attribute__((address_space(1))) unsigned int*)(uintptr_t)gp,
                (__attribute__((address_space(3))) unsigned int*)(uintptr_t)lp,
                16, 0, 0);
        }
        __syncthreads();
        bf16x8 a[4], b[4];
#pragma unroll
        for (int i = 0; i < 4; i++)
            a[i] = *(const bf16x8*)&As[(wm * 64 + i * 16 + l16) * 32 + quad * 8];
#pragma unroll
        for (int j = 0; j < 4; j++)
            b[j] = *(const bf16x8*)&Bs[(wn * 64 + j * 16 + l16) * 32 + quad * 8];
#pragma unroll
        for (int i = 0; i < 4; i++)
#pragma unroll
            for (int j = 0; j < 4; j++)
                acc[i][j] = __builtin_amdgcn_mfma_f32_16x16x32_bf16(a[i], b[j], acc[i][j], 0, 0, 0);
        __syncthreads();
    }

#pragma unroll
    for (int i = 0; i < 4; i++) {
        int gm0 = row0 + wm * 64 + i * 16 + quad * 4;
#pragma unroll
        for (int r = 0; r < 4; r++) {
            int gm = gm0 + r;
            if (gm < N_) {
                int col = col0 + wn * 64 + l16;
                size_t base = (size_t)gm * NG_ + col;
#pragma unroll
                for (int j = 0; j < 4; j++)
                    C[base + j * 16] = acc[i][j][r] + bias[col + j * 16];
            }
        }
    }
}

// msg[e,o] = (he[e,:]/64).(fp8 V[row[e],o,:]) + outb[row[e],o]; atomicAdd into agg[col[e],o]
__global__ void k_msg(const int* __restrict__ ei, const float* __restrict__ he,
                      const unsigned char* __restrict__ V8, const float* __restrict__ outb,
                      float* __restrict__ agg) {
    int e = blockIdx.x, o = threadIdx.x;
    __shared__ float hs[KH_];
    if (o < KH_) hs[o] = he[e * KH_ + o] * VSCALE_INV;
    __syncthreads();
    int r = ei[e], c = ei[E_ + e];
    float acc = outb[(size_t)r * H_ + o];
    const uint4* vp = reinterpret_cast<const uint4*>(V8 + (size_t)r * NV_ + (size_t)o * KH_);
#pragma unroll
    for (int q = 0; q < 8; q++) {       // 8 x uint4 = 128 fp8
        uint4 u = vp[q];
        const float* hp = hs + q * 16;
        f32x2 f;
        f = __builtin_amdgcn_cvt_pk_f32_fp8(u.x, false); acc += hp[0]  * f.x + hp[1]  * f.y;
        f = __builtin_amdgcn_cvt_pk_f32_fp8(u.x, true);  acc += hp[2]  * f.x + hp[3]  * f.y;
        f = __builtin_amdgcn_cvt_pk_f32_fp8(u.y, false); acc += hp[4]  * f.x + hp[5]  * f.y;
        f = __builtin_amdgcn_cvt_pk_f32_fp8(u.y, true);  acc += hp[6]  * f.x + hp[7]  * f.y;
        f = __builtin_amdgcn_cvt_pk_f32_fp8(u.z, false); acc += hp[8]  * f.x + hp[9]  * f.y;
        f = __builtin_amdgcn_cvt_pk_f32_fp8(u.z, true);  acc += hp[10] * f.x + hp[11] * f.y;
        f = __builtin_amdgcn_cvt_pk_f32_fp8(u.w, false); acc += hp[12] * f.x + hp[13] * f.y;
        f = __builtin_amdgcn_cvt_pk_f32_fp8(u.w, true);  acc += hp[14] * f.x + hp[15] * f.y;
    }
    atomicAdd(&agg[(size_t)c * H_ + o], acc);
}

// Mbf = bf16(relu(agg / max(counts,1) + conv_b))
__global__ void k_m(const float* __restrict__ agg, const float* __restrict__ counts,
                    const float* __restrict__ conv_b, __hip_bfloat16* __restrict__ Mbf) {
    int i = blockIdx.x * blockDim.x + threadIdx.x;
    if (i >= N_ * H_) return;
    int n = i >> 8, o = i & 255;
    float c = fmaxf(counts[n], 1.0f);
    Mbf[i] = __float2bfloat16(fmaxf(agg[i] / c + conv_b[o], 0.f));
}

// GRU pointwise; refreshes Abf = bf16(h); re-zeroes aggm for the next iteration.
__global__ void k_gru_update(const float* __restrict__ gi, const float* __restrict__ gh,
                             float* __restrict__ h, __hip_bfloat16* __restrict__ Abf,
                             float* __restrict__ aggm) {
    int i = blockIdx.x * blockDim.x + threadIdx.x;
    if (i >= N_ * H_) return;
    aggm[i] = 0.f;
    int n = i >> 8, j = i & 255;
    const float* gip = gi + (size_t)n * NG_;
    const float* ghp = gh + (size_t)n * NG_;
    float r = 1.f / (1.f + expf(-(gip[j] + ghp[j])));
    float z = 1.f / (1.f + expf(-(gip[H_ + j] + ghp[H_ + j])));
    float nn = tanhf(gip[2 * H_ + j] + r * ghp[2 * H_ + j]);
    float hv = (1.f - z) * nn + z * h[i];
    h[i] = hv;
    Abf[i] = __float2bfloat16(hv);
}

// batchnorm stats over E rows, per column j   grid 128, block 256
__global__ void k_bnstats(const float* __restrict__ h1, float* __restrict__ mu,
                          float* __restrict__ rsig) {
    int j = blockIdx.x, t = threadIdx.x;
    float s = 0.f, ss = 0.f;
    for (int e = t; e < E_; e += 256) {
        float v = h1[(size_t)e * 128 + j];
        s += v;
        ss += v * v;
    }
    __shared__ float rs[256], rss[256];
    rs[t] = s; rss[t] = ss;
    __syncthreads();
    for (int off = 128; off > 0; off >>= 1) {
        if (t < off) { rs[t] += rs[t + off]; rss[t] += rss[t + off]; }
        __syncthreads();
    }
    if (t == 0) {
        float m_ = rs[0] / E_;
        float v_ = rss[0] / E_ - m_ * m_;
        mu[j] = m_;
        rsig[j] = rsqrtf(v_ + 1e-5f);
    }
}

// precs[e] = relu(bn(h1[e])) . l6_W2 + b
__global__ void k_precs(const float* __restrict__ h1, const float* __restrict__ mu,
                        const float* __restrict__ rsig, const float* __restrict__ g,
                        const float* __restrict__ bb, const float* __restrict__ W2,
                        const float* __restrict__ b2, float* __restrict__ out) {
    int e = blockIdx.x * blockDim.x + threadIdx.x;
    if (e >= E_) return;
    float acc = b2[0];
#pragma unroll 4
    for (int j = 0; j < 128; j++) {
        float v = (h1[(size_t)e * 128 + j] - mu[j]) * rsig[j] * g[j] + bb[j];
        acc += fmaxf(v, 0.f) * W2[j];
    }
    out[(size_t)E_ * 242 + e] = acc;
}

extern "C" void kernel_launch(void* const* d_in, const int* in_sizes, int n_in,
                              void* d_out, int out_size, void* d_ws, size_t ws_size,
                              hipStream_t stream) {
    const int*   x        = (const int*)  d_in[0];
    const float* pos      = (const float*)d_in[1];
    const int*   ei       = (const int*)  d_in[2];
    const float* edge_atr = (const float*)d_in[3];
    const float* emb      = (const float*)d_in[4];
    const float* lin0_W   = (const float*)d_in[5];
    const float* lin0_b   = (const float*)d_in[6];
    const float* mlp1_W   = (const float*)d_in[7];
    const float* mlp1_b   = (const float*)d_in[8];
    const float* mlp2_W   = (const float*)d_in[9];
    const float* mlp2_b   = (const float*)d_in[10];
    const float* conv_b   = (const float*)d_in[11];
    const float* gru_Wih  = (const float*)d_in[12];
    const float* gru_Whh  = (const float*)d_in[13];
    const float* gru_bih  = (const float*)d_in[14];
    const float* gru_bhh  = (const float*)d_in[15];
    const float* lin1_W   = (const float*)d_in[16];
    const float* lin1_b   = (const float*)d_in[17];
    const float* lin2_W   = (const float*)d_in[18];
    const float* lin2_b   = (const float*)d_in[19];
    const float* l6_W1    = (const float*)d_in[20];
    const float* l6_b1    = (const float*)d_in[21];
    const float* bn_g     = (const float*)d_in[22];
    const float* bn_b     = (const float*)d_in[23];
    const float* l6_W2    = (const float*)d_in[24];
    const float* l6_b2    = (const float*)d_in[25];
    float* out = (float*)d_out;

    // workspace layout
    char* w = (char*)d_ws;
    size_t off = 0;
    auto alloc = [&](size_t bytes) -> void* {
        void* p = w + off;
        off = (off + bytes + 255) & ~(size_t)255;
        return p;
    };
    float* hbuf   = (float*)alloc((size_t)N_ * H_ * 4);
    float* aggm   = (float*)alloc((size_t)N_ * H_ * 4);
    float* outb   = (float*)alloc((size_t)N_ * H_ * 4);
    float* he     = (float*)alloc((size_t)E_ * KH_ * 4);
    float* gi     = (float*)alloc((size_t)N_ * NG_ * 4);
    float* gh     = (float*)alloc((size_t)N_ * NG_ * 4);
    float* h1     = (float*)alloc((size_t)E_ * 128 * 4);
    float* counts = (float*)alloc((size_t)N_ * 4);
    float* mu     = (float*)alloc(128 * 4);
    float* rsig   = (float*)alloc(128 * 4);
    unsigned char* V8      = (unsigned char*)alloc((size_t)N_ * NV_);          // 65.5 MB fp8
    __hip_bfloat16* Abf    = (__hip_bfloat16*)alloc((size_t)MPAD_ * H_ * 2);
    __hip_bfloat16* Mbf    = (__hip_bfloat16*)alloc((size_t)MPAD_ * H_ * 2);
    __hip_bfloat16* Bt     = (__hip_bfloat16*)alloc((size_t)NV_ * H_ * 2);     // 16.8 MB
    __hip_bfloat16* WihB   = (__hip_bfloat16*)alloc((size_t)NG_ * H_ * 2);
    __hip_bfloat16* WhhB   = (__hip_bfloat16*)alloc((size_t)NG_ * H_ * 2);
    __hip_bfloat16* lin1Wb = (__hip_bfloat16*)alloc((size_t)H_ * 2 * H_ * 2);
    __hip_bfloat16* l6W1b  = (__hip_bfloat16*)alloc((size_t)128 * 2 * H_ * 2);
    __hip_bfloat16* lin2Wb = (__hip_bfloat16*)alloc((size_t)H_ * H_ * 2);
    __hip_bfloat16* BtB    = (__hip_bfloat16*)alloc((size_t)H_ * H_ * 2);
    __hip_bfloat16* Cbf    = (__hip_bfloat16*)alloc((size_t)E_ * 2 * H_ * 2);
    __hip_bfloat16* o1bf   = (__hip_bfloat16*)alloc((size_t)E_ * H_ * 2);

    k_lin0<<<MPAD_, 256, 0, stream>>>(x, pos, emb, lin0_W, lin0_b, hbuf, Abf, aggm);
    k_he<<<E_, 128, 0, stream>>>(edge_atr, mlp1_W, mlp1_b, he);
    hipMemsetAsync(counts, 0, (size_t)N_ * 4, stream);
    k_counts<<<(E_ + 255) / 256, 256, 0, stream>>>(ei, counts);
    k_trans_bt<<<dim3(NV_ / 64, H_ / 32), 256, 0, stream>>>(mlp2_W, Bt);
    k_prep_w<<<768, 256, 0, stream>>>(gru_Wih, gru_Whh, lin1_W, l6_W1, lin2_W, mlp2_b,
                                      WihB, WhhB, lin1Wb, l6W1b, lin2Wb, BtB);

    for (int it = 0; it < 3; it++) {
        // outb = Abf @ BtB^T (fp32, no bias)
        k_gemm_nt<256, false, false><<<dim3(2, MPAD_ / 128), 256, 0, stream>>>(
            Abf, BtB, outb, nullptr, nullptr, H_, H_, N_);
        // V-GEMM: grid (256,16), col-fastest, 256 % 8 == 0 (XCD-stable col mapping)
        dim3 gv(NV_ / 128, MPAD_ / 128);
        k_gemm_V_mfma<<<gv, 256, 0, stream>>>(Abf, Bt, V8);
        k_msg<<<E_, 256, 0, stream>>>(ei, he, V8, outb, aggm);
        k_m<<<(N_ * H_ + 255) / 256, 256, 0, stream>>>(aggm, counts, conv_b, Mbf);
        dim3 gg(NG_ / 128, MPAD_ / 128, 2);
        k_gemm_gru_mfma<<<gg, 256, 0, stream>>>(Mbf, Abf, WihB, WhhB,
                                                gru_bih, gru_bhh, gi, gh);
        k_gru_update<<<(N_ * H_ + 255) / 256, 256, 0, stream>>>(gi, gh, hbuf, Abf, aggm);
    }

    k_concat<<<E_, 256, 0, stream>>>(ei, hbuf, Cbf);
    k_gemm_nt<512, true, true><<<dim3(2, E_ / 128), 256, 0, stream>>>(
        Cbf, lin1Wb, nullptr, o1bf, lin1_b, H_, H_, E_);
    k_gemm_nt<256, false, false><<<dim3(2, E_ / 128), 256, 0, stream>>>(
        o1bf, lin2Wb, out, nullptr, lin2_b, 242, 242, E_);
    k_gemm_nt<512, false, false><<<dim3(1, E_ / 128), 256, 0, stream>>>(
        Cbf, l6W1b, h1, nullptr, l6_b1, 128, 128, E_);
    k_bnstats<<<128, 256, 0, stream>>>(h1, mu, rsig);
    k_precs<<<(E_ + 255) / 256, 256, 0, stream>>>(h1, mu, rsig, bn_g, bn_b, l6_W2, l6_b2, out);
}